// Round 8
// baseline (976.704 us; speedup 1.0000x reference)
//
#include <hip/hip_runtime.h>

// ConvexPolytopeManifold: dual-PGD QP projection. B=4096, n=512, m=1024.
// Round 25: ALGEBRAIC epilogue cut on top of r24 (best measured 968.5us).
// PGD step lam<-relu(lam - s(lam@Q - c)) == relu(lam@G + sc) with
// G = I - s*Q (fp16, built in the Q-dispatch epilogue) and sc = fp16(s*c).
// EPI2/EPI3 epilogues drop the lamIn load entirely (-8MB/iter, -2 VMEM
// ops/thread, shorter dep chain). EPI4 (active test) keeps raw Q: rewriting
// it through G would divide by s=0.01 and amplify accum noise 100x vs
// TOL=1e-5. Numerics class unchanged (fp16 rel 2^-11 either way); lam
// self-term now rides the f32 MFMA accumulator.
// K-loop identical to r22/r24: 64Mx128N, 8 waves (32x32 tiles), 3-buffer
// counted-vmcnt (6/3/0), raw barriers, setprio, XOR swizzle, XCD grid.
// Epilogue path identical to r24: acc->LDS(132-stride)->coalesced 16B I/O.
// Prediction: -0.5..-1.5us on the 59 hot dispatches -> ~890-940us.
//
// math:
//   Q = A@A^T; G = I - s*Q; y = x+u; c = y@A^T - b; sc = s*c
//   lam1 = relu(sc); 49x lam = relu(lam@G + sc)
//   active = (c - lam@Q >= -TOL)
//   masked = (u@A^T)*active; scm = s*masked; lam1 = relu(scm)
//   9x lam = relu(lam@G + scm) * active
//   out = u - lam@A

#define TOLV 1e-5f
#define STEPV 0.01f

typedef __attribute__((ext_vector_type(8))) _Float16 half8;
typedef __attribute__((ext_vector_type(4))) float floatx4;
typedef unsigned short ushort_t;
typedef __attribute__((ext_vector_type(8))) unsigned short ushort8v;

#define GLDS(gptr, lptr) \
    __builtin_amdgcn_global_load_lds( \
        (const __attribute__((address_space(1))) void*)(gptr), \
        (__attribute__((address_space(3))) void*)(lptr), 16, 0, 0)

__device__ inline ushort_t f2h(float f) {
    union { _Float16 h; ushort_t u; } c; c.h = (_Float16)f;   // RNE
    return c.u;
}
__device__ inline float h2f(ushort_t u) {
    union { ushort_t u; _Float16 h; } c; c.u = u;
    return (float)c.h;
}

__global__ void addcast_kernel(const float* __restrict__ x, const float* __restrict__ u,
                               ushort_t* __restrict__ yh, ushort_t* __restrict__ uh, int n) {
    int idx = (blockIdx.x * blockDim.x + threadIdx.x) * 4;
    if (idx < n) {
        float4 xv = *(const float4*)(x + idx);
        float4 uv = *(const float4*)(u + idx);
        ushort4 yo, uo;
        yo.x = f2h(xv.x + uv.x); yo.y = f2h(xv.y + uv.y);
        yo.z = f2h(xv.z + uv.z); yo.w = f2h(xv.w + uv.w);
        uo.x = f2h(uv.x); uo.y = f2h(uv.y); uo.z = f2h(uv.z); uo.w = f2h(uv.w);
        *(ushort4*)(yh + idx) = yo;
        *(ushort4*)(uh + idx) = uo;
    }
}

__global__ void cvt_h_kernel(const float* __restrict__ src, ushort_t* __restrict__ dst, int n) {
    int idx = (blockIdx.x * blockDim.x + threadIdx.x) * 4;
    if (idx < n) {
        float4 v = *(const float4*)(src + idx);
        ushort4 o;
        o.x = f2h(v.x); o.y = f2h(v.y); o.z = f2h(v.z); o.w = f2h(v.w);
        *(ushort4*)(dst + idx) = o;
    }
}

__global__ void transpose_cast_kernel(const float* __restrict__ A, ushort_t* __restrict__ AT,
                                      int m, int n) {
    __shared__ float t[32][33];
    int bx = blockIdx.x * 32;
    int by = blockIdx.y * 32;
    int tx = threadIdx.x & 31, ty = threadIdx.x >> 5;   // 32 x 8
#pragma unroll
    for (int i = 0; i < 32; i += 8)
        t[ty + i][tx] = A[(size_t)(by + ty + i) * n + bx + tx];
    __syncthreads();
#pragma unroll
    for (int i = 0; i < 32; i += 8)
        AT[(size_t)(bx + ty + i) * m + by + tx] = f2h(t[tx][ty + i]);
}

// ---------------- fp16 MFMA GEMM, 64x128, 8 waves, counted-vmcnt 3-buffer -----
// C = X @ W^T. X=[M,K] fp16, W=[N,K] fp16. 512 thr = 8 waves.
// Tile 64Mx128N, BK=64, wave tile 32x32 (2x2 of 16x16x32 f16), waves 2Mx4N.
// XOR-swizzled LDS; XCD-aware 1D grid. 3 GLDS/thread/tile.
// Epilogue: acc -> LDS (f32, stride 132) -> thread-linear coalesced I/O.
// EPI: 0 Q+G:    lamOut = fp16(v); cHout = fp16(I - s*v)
//      1 c+lam1: cv=v-bvec[col]; cFout=cv; cHout=f2h(s*cv); lamOut=f2h(s*relu(cv))
//      2 iter:   nv=relu(v + h2f(sc)); lamOut=f2h(nv)
//      3 iter*act
//      4 act:    actOut = (cF - v >= -TOL) ? 1 : 0  (fp16)   [v = lam@Q]
//      5 masked+lam1: mv=v*act; cHout=f2h(s*mv); lamOut=f2h(s*relu(mv))
//      6 final:  outF = uin - v
template<int EPI>
__global__ __launch_bounds__(512, 4)
void mfma_g(const ushort_t* __restrict__ X, const ushort_t* __restrict__ W,
            const ushort_t* __restrict__ lamIn, const float* __restrict__ cF,
            const ushort_t* __restrict__ cH, const ushort_t* __restrict__ actb,
            ushort_t* __restrict__ lamOut, float* __restrict__ cFout,
            ushort_t* __restrict__ cHout, ushort_t* __restrict__ actOut,
            const float* __restrict__ uin, float* __restrict__ outF,
            const float* __restrict__ bvec,
            int M, int N, int K) {
    // As[3][64*64] then Bs[3][128*64]; epilogue aliases front as [64][132] f32.
    __shared__ short SMEM[3 * 64 * 64 + 3 * 128 * 64];   // 72 KB, 2 blk/CU

    const int tid = threadIdx.x;
    const int w = tid >> 6;              // 0..7
    const int lane = tid & 63;

    const int nbm = M >> 6;
    const int spx = nbm >> 3;
    const int xcd = blockIdx.x & 7;
    const int loc = blockIdx.x >> 3;
    const int bm = (xcd * spx + (loc % spx)) << 6;
    const int bn = (loc / spx) << 7;

    const int wm = (w & 1) * 32;         // 2 wave-rows along M
    const int wn = (w >> 1) * 32;        // 4 wave-cols along N
    const int quad = lane >> 4;
    const int l15 = lane & 15;

    const int ldr = lane >> 3;
    const int csw = ((lane & 7) ^ ldr) * 8;

    const ushort_t* Xb = X + (size_t)bm * K + csw;
    const ushort_t* Wb = W + (size_t)bn * K + csw;

    floatx4 acc[2][2] = {};

    const int KT = K >> 6;

    short* const AsBase = SMEM;                 // 3 x 4096 shorts
    short* const BsBase = SMEM + 3 * 64 * 64;   // 3 x 8192 shorts

    // stage tile kt into buffer bi: 1 GLDS (As) + 2 GLDS (Bs) per thread
    auto STAGE = [&](int kt, int bi) {
        const int ko = kt << 6;
        GLDS(Xb + (size_t)(w * 8 + ldr) * K + ko, AsBase + bi * 4096 + (w * 8) * 64);
#pragma unroll
        for (int t = 0; t < 2; ++t)
            GLDS(Wb + (size_t)(w * 16 + t * 8 + ldr) * K + ko,
                 BsBase + bi * 8192 + (w * 16 + t * 8) * 64);
    };

    // prologue: stage tiles 0 and 1 (6 loads in flight)
    STAGE(0, 0);
    STAGE(1, 1);

    int cur = 0;
    for (int kt = 0; kt < KT; ++kt) {
        // issue stage(t+2), then counted wait: drain ONLY stage(t).
        if (kt + 2 < KT) {
            int nb = cur + 2; if (nb >= 3) nb -= 3;
            STAGE(kt + 2, nb);
            asm volatile("s_waitcnt vmcnt(6)" ::: "memory");
        } else if (kt + 1 < KT) {
            asm volatile("s_waitcnt vmcnt(3)" ::: "memory");
        } else {
            asm volatile("s_waitcnt vmcnt(0)" ::: "memory");
        }
        __builtin_amdgcn_s_barrier();          // buf[cur] valid for all waves

        __builtin_amdgcn_s_setprio(1);
#pragma unroll
        for (int kk = 0; kk < 2; ++kk) {
            const int sw = ((kk * 4 + quad) ^ (l15 & 7)) * 8;
            half8 af[2], bfr[2];
#pragma unroll
            for (int i = 0; i < 2; ++i)
                af[i] = *(const half8*)(AsBase + cur * 4096 + (wm + i * 16 + l15) * 64 + sw);
#pragma unroll
            for (int i = 0; i < 2; ++i)
                bfr[i] = *(const half8*)(BsBase + cur * 8192 + (wn + i * 16 + l15) * 64 + sw);
#pragma unroll
            for (int mt = 0; mt < 2; ++mt)
#pragma unroll
                for (int nt = 0; nt < 2; ++nt)
                    acc[mt][nt] = __builtin_amdgcn_mfma_f32_16x16x32_f16(
                        af[mt], bfr[nt], acc[mt][nt], 0, 0, 0);
        }
        __builtin_amdgcn_s_setprio(0);
        __builtin_amdgcn_sched_barrier(0);     // pin reads+MFMA above barrier2
        __builtin_amdgcn_s_barrier();          // all reads of buf[cur] done ->
                                               // safe target for stage(kt+3)
        ++cur; if (cur >= 3) cur -= 3;
    }

    // ---- epilogue: acc -> LDS (f32, stride 132) -> thread-linear coalesced ----
    __builtin_amdgcn_sched_barrier(0);         // keep ds_writes below last barrier
    float* Cs = (float*)SMEM;                  // 64 x 132 f32 = 33792 B

    // write acc in C/D layout: row = quad*4+r, col = lane&15 per 16x16 tile
#pragma unroll
    for (int mt = 0; mt < 2; ++mt)
#pragma unroll
        for (int nt = 0; nt < 2; ++nt)
#pragma unroll
            for (int r = 0; r < 4; ++r) {
                int rl = wm + mt * 16 + quad * 4 + r;
                int cl = wn + nt * 16 + l15;
                Cs[rl * 132 + cl] = acc[mt][nt][r];
            }
    __syncthreads();

    // linear phase: thread t -> row t>>3 (0..63), col chunk (t&7)*16
    const int rl = tid >> 3;
    const int c0 = (tid & 7) * 16;
    const int grow = bm + rl;
    const int gcol = bn + c0;
    const size_t gidx = (size_t)grow * N + gcol;

    float v[16];
#pragma unroll
    for (int j = 0; j < 4; ++j)
        *(floatx4*)(v + 4 * j) = *(const floatx4*)(Cs + rl * 132 + c0 + 4 * j);

    if (EPI == 0) {
        ushort_t hq[16], hg[16];
#pragma unroll
        for (int j = 0; j < 16; ++j) {
            hq[j] = f2h(v[j]);
            float d = (grow == gcol + j) ? 1.0f : 0.0f;
            hg[j] = f2h(d - STEPV * v[j]);
        }
        *(ushort8v*)(lamOut + gidx) = *(ushort8v*)hq;
        *(ushort8v*)(lamOut + gidx + 8) = *(ushort8v*)(hq + 8);
        *(ushort8v*)(cHout + gidx) = *(ushort8v*)hg;
        *(ushort8v*)(cHout + gidx + 8) = *(ushort8v*)(hg + 8);
    } else if (EPI == 1) {
        float bv[16];
#pragma unroll
        for (int j = 0; j < 4; ++j)
            *(floatx4*)(bv + 4 * j) = *(const floatx4*)(bvec + gcol + 4 * j);
        ushort_t ch[16], lo[16];
        float cf[16];
#pragma unroll
        for (int j = 0; j < 16; ++j) {
            float cv = v[j] - bv[j];
            cf[j] = cv;
            ch[j] = f2h(STEPV * cv);                    // sc = s*c
            lo[j] = f2h(STEPV * fmaxf(cv, 0.0f));       // lam1
        }
#pragma unroll
        for (int j = 0; j < 4; ++j)
            *(floatx4*)(cFout + gidx + 4 * j) = *(floatx4*)(cf + 4 * j);
        *(ushort8v*)(cHout + gidx) = *(ushort8v*)ch;
        *(ushort8v*)(cHout + gidx + 8) = *(ushort8v*)(ch + 8);
        *(ushort8v*)(lamOut + gidx) = *(ushort8v*)lo;
        *(ushort8v*)(lamOut + gidx + 8) = *(ushort8v*)(lo + 8);
    } else if (EPI == 2 || EPI == 3) {
        // v = lam@G ; nv = relu(v + sc) [* act]
        ushort_t sc[16], ab[16], lo[16];
        *(ushort8v*)sc = *(const ushort8v*)(cH + gidx);
        *(ushort8v*)(sc + 8) = *(const ushort8v*)(cH + gidx + 8);
        if (EPI == 3) {
            *(ushort8v*)ab = *(const ushort8v*)(actb + gidx);
            *(ushort8v*)(ab + 8) = *(const ushort8v*)(actb + gidx + 8);
        }
#pragma unroll
        for (int j = 0; j < 16; ++j) {
            float nv = fmaxf(v[j] + h2f(sc[j]), 0.0f);
            if (EPI == 3) nv *= h2f(ab[j]);
            lo[j] = f2h(nv);
        }
        *(ushort8v*)(lamOut + gidx) = *(ushort8v*)lo;
        *(ushort8v*)(lamOut + gidx + 8) = *(ushort8v*)(lo + 8);
    } else if (EPI == 4) {
        float cf[16];
#pragma unroll
        for (int j = 0; j < 4; ++j)
            *(floatx4*)(cf + 4 * j) = *(const floatx4*)(cF + gidx + 4 * j);
        ushort_t ao[16];
#pragma unroll
        for (int j = 0; j < 16; ++j)
            ao[j] = (cf[j] - v[j] >= -TOLV) ? (ushort_t)0x3C00 : (ushort_t)0;
        *(ushort8v*)(actOut + gidx) = *(ushort8v*)ao;
        *(ushort8v*)(actOut + gidx + 8) = *(ushort8v*)(ao + 8);
    } else if (EPI == 5) {
        ushort_t ab[16], ch[16], lo[16];
        *(ushort8v*)ab = *(const ushort8v*)(actb + gidx);
        *(ushort8v*)(ab + 8) = *(const ushort8v*)(actb + gidx + 8);
#pragma unroll
        for (int j = 0; j < 16; ++j) {
            float mv = v[j] * h2f(ab[j]);
            ch[j] = f2h(STEPV * mv);                    // sc = s*masked
            lo[j] = f2h(STEPV * fmaxf(mv, 0.0f));       // lam1
        }
        *(ushort8v*)(cHout + gidx) = *(ushort8v*)ch;
        *(ushort8v*)(cHout + gidx + 8) = *(ushort8v*)(ch + 8);
        *(ushort8v*)(lamOut + gidx) = *(ushort8v*)lo;
        *(ushort8v*)(lamOut + gidx + 8) = *(ushort8v*)(lo + 8);
    } else if (EPI == 6) {
        float uv[16], ov[16];
#pragma unroll
        for (int j = 0; j < 4; ++j)
            *(floatx4*)(uv + 4 * j) = *(const floatx4*)(uin + gidx + 4 * j);
#pragma unroll
        for (int j = 0; j < 16; ++j) ov[j] = uv[j] - v[j];
#pragma unroll
        for (int j = 0; j < 4; ++j)
            *(floatx4*)(outF + gidx + 4 * j) = *(floatx4*)(ov + 4 * j);
    }
}

static inline int grid1d(int M, int N) { return (M >> 6) * (N >> 7); }

extern "C" void kernel_launch(void* const* d_in, const int* in_sizes, int n_in,
                              void* d_out, int out_size, void* d_ws, size_t ws_size,
                              hipStream_t stream) {
    const float* x = (const float*)d_in[0];  // [B,n]
    const float* u = (const float*)d_in[1];  // [B,n]
    const float* A = (const float*)d_in[2];  // [m,n]
    const float* b = (const float*)d_in[3];  // [m]
    float* out = (float*)d_out;              // [B,n]

    const int B = 4096, n = 512, m = 1024;
    const size_t Bm = (size_t)B * m;
    const size_t Bn = (size_t)B * n;

    ushort_t* A_h   = (ushort_t*)d_ws;             // [m,n]
    ushort_t* AT_h  = A_h + (size_t)m * n;         // [n,m]
    ushort_t* y_h   = AT_h + (size_t)n * m;        // [B,n]
    ushort_t* u_h   = y_h + Bn;                    // [B,n]
    ushort_t* Q_h   = u_h + Bn;                    // [m,m]
    ushort_t* lamA  = Q_h + (size_t)m * m;         // [B,m] fp16
    ushort_t* lamB  = lamA + Bm;                   // [B,m] fp16
    ushort_t* act   = lamB + Bm;                   // [B,m] fp16 0/1
    ushort_t* cHbuf = act + Bm;                    // [B,m] fp16 (sc, then s*masked)
    float* cFbuf = (float*)(cHbuf + Bm);           // [B,m] f32 (c, for act test)
    ushort_t* G_h   = (ushort_t*)(cFbuf + Bm);     // [m,m] fp16: G = I - s*Q

    dim3 blk(512);

    addcast_kernel<<<(int)(Bn / 4 + 255) / 256, 256, 0, stream>>>(x, u, y_h, u_h, (int)Bn);
    cvt_h_kernel<<<(m * n / 4 + 255) / 256, 256, 0, stream>>>(A, A_h, m * n);
    transpose_cast_kernel<<<dim3(n / 32, m / 32), dim3(256), 0, stream>>>(A, AT_h, m, n);

    // Q = fp16(A @ A^T); G = fp16(I - s*Q)
    mfma_g<0><<<grid1d(m, m), blk, 0, stream>>>(
        A_h, A_h, nullptr, nullptr, nullptr, nullptr,
        Q_h, nullptr, G_h, nullptr, nullptr, nullptr, nullptr, m, m, n);

    // c = y@A^T - b (cF f32 + sc fp16); lamA = fp16(lam1 = s*relu(c))
    mfma_g<1><<<grid1d(B, m), blk, 0, stream>>>(
        y_h, A_h, nullptr, nullptr, nullptr, nullptr,
        lamA, cFbuf, cHbuf, nullptr, nullptr, nullptr, b, B, m, n);

    // phase 1: 49 more iterations: lam = relu(lam@G + sc)
    ushort_t* lin = lamA; ushort_t* lout = lamB;
    for (int it = 0; it < 49; ++it) {
        mfma_g<2><<<grid1d(B, m), blk, 0, stream>>>(
            lin, G_h, nullptr, nullptr, cHbuf, nullptr,
            lout, nullptr, nullptr, nullptr, nullptr, nullptr, nullptr, B, m, m);
        ushort_t* t = lin; lin = lout; lout = t;
    }

    // active = (c - lam50@Q >= -TOL)   [raw Q: no 1/s noise amplification]
    mfma_g<4><<<grid1d(B, m), blk, 0, stream>>>(
        lin, Q_h, nullptr, cFbuf, nullptr, nullptr,
        nullptr, nullptr, nullptr, act, nullptr, nullptr, nullptr, B, m, m);

    // masked = (u@A^T)*active -> sc; lamA = fp16(lam1 = s*relu(masked))
    mfma_g<5><<<grid1d(B, m), blk, 0, stream>>>(
        u_h, A_h, nullptr, nullptr, nullptr, act,
        lamA, nullptr, cHbuf, nullptr, nullptr, nullptr, nullptr, B, m, n);

    // phase 2: 9 more iterations: lam = relu(lam@G + sc) * act
    lin = lamA; lout = lamB;
    for (int it = 0; it < 9; ++it) {
        mfma_g<3><<<grid1d(B, m), blk, 0, stream>>>(
            lin, G_h, nullptr, nullptr, cHbuf, act,
            lout, nullptr, nullptr, nullptr, nullptr, nullptr, nullptr, B, m, m);
        ushort_t* t = lin; lin = lout; lout = t;
    }

    // out = u - lam @ A
    mfma_g<6><<<grid1d(B, n), blk, 0, stream>>>(
        lin, AT_h, nullptr, nullptr, nullptr, nullptr,
        nullptr, nullptr, nullptr, nullptr, u, out, nullptr, B, n, m);
}

// Round 10
// 893.957 us; speedup vs baseline: 1.0926x; 1.0926x over previous
//
#include <hip/hip_runtime.h>

// ConvexPolytopeManifold: dual-PGD QP projection. B=4096, n=512, m=1024.
// Round 27: resubmit of round-26 (bench infra failed: "container failed
// twice" — third occurrence of this acquisition-level flake; rounds 19/23
// both benched clean on identical resubmission). Hazard logic re-audited:
// reads of the re-staged buffer complete (lgkmcnt before MFMA) before the
// wave reaches the barrier; hipcc does not sink LDS ops across s_barrier
// (T3/m201 pattern); vmcnt counts checked for KT=8/16; epilogue aliasing
// protected by the added __syncthreads.
//
// Round-26 change (unchanged): SINGLE-BARRIER K-loop on r24 base (968.5us).
// r25 (G=I-sQ operand cut) was +8us and worse absmax -> REVERTED; epilogue
// operand loads are fully hidden. Remaining lever in the hot dispatch
// (~15us vs ~8.4us composed floor): sync count — 2 barriers/K-tile.
// Change: move STAGE(kt+2) to AFTER barrier1. Then barrier1 itself orders
// the overwrite hazard (a wave's iter-(kt-1) ds_reads are consumed before
// it reaches barrier1(kt), so buf[(kt+2)%3]==buf[(kt-1)%3] has no readers
// once any wave passes barrier1(kt)) -> barrier2 + sched_barrier pins
// deleted. T3 minimal recipe: one vmcnt+barrier per tile, STAGE issued
// before ds_read+MFMA. vmcnt: steady 3 (drains stage(kt), stage(kt+1)
// stays in flight), tail 0. Epilogue gains one __syncthreads() before the
// Cs ds_writes (they alias As; previously protected by final barrier2).
// 32 -> 17 barriers/dispatch. Prediction: -0.5..-1.5us x 62 dispatches
// -> ~905-940us, absmax back to 0.046875.
//
// math:
//   Q = A@A^T; y = x+u; c = y@A^T - b
//   lam1 = step*relu(c); 49x lam = relu(lam - 0.01*(lam@Q - c))
//   active = (c - lam@Q >= -TOL)
//   masked = (u@A^T) * active; lam1 = step*relu(masked)
//   9x lam = relu(lam - 0.01*(lam@Q - masked)) * active
//   out = u - lam@A

#define TOLV 1e-5f
#define STEPV 0.01f

typedef __attribute__((ext_vector_type(8))) _Float16 half8;
typedef __attribute__((ext_vector_type(4))) float floatx4;
typedef unsigned short ushort_t;
typedef __attribute__((ext_vector_type(8))) unsigned short ushort8v;

#define GLDS(gptr, lptr) \
    __builtin_amdgcn_global_load_lds( \
        (const __attribute__((address_space(1))) void*)(gptr), \
        (__attribute__((address_space(3))) void*)(lptr), 16, 0, 0)

__device__ inline ushort_t f2h(float f) {
    union { _Float16 h; ushort_t u; } c; c.h = (_Float16)f;   // RNE
    return c.u;
}
__device__ inline float h2f(ushort_t u) {
    union { ushort_t u; _Float16 h; } c; c.u = u;
    return (float)c.h;
}

__global__ void addcast_kernel(const float* __restrict__ x, const float* __restrict__ u,
                               ushort_t* __restrict__ yh, ushort_t* __restrict__ uh, int n) {
    int idx = (blockIdx.x * blockDim.x + threadIdx.x) * 4;
    if (idx < n) {
        float4 xv = *(const float4*)(x + idx);
        float4 uv = *(const float4*)(u + idx);
        ushort4 yo, uo;
        yo.x = f2h(xv.x + uv.x); yo.y = f2h(xv.y + uv.y);
        yo.z = f2h(xv.z + uv.z); yo.w = f2h(xv.w + uv.w);
        uo.x = f2h(uv.x); uo.y = f2h(uv.y); uo.z = f2h(uv.z); uo.w = f2h(uv.w);
        *(ushort4*)(yh + idx) = yo;
        *(ushort4*)(uh + idx) = uo;
    }
}

__global__ void cvt_h_kernel(const float* __restrict__ src, ushort_t* __restrict__ dst, int n) {
    int idx = (blockIdx.x * blockDim.x + threadIdx.x) * 4;
    if (idx < n) {
        float4 v = *(const float4*)(src + idx);
        ushort4 o;
        o.x = f2h(v.x); o.y = f2h(v.y); o.z = f2h(v.z); o.w = f2h(v.w);
        *(ushort4*)(dst + idx) = o;
    }
}

__global__ void transpose_cast_kernel(const float* __restrict__ A, ushort_t* __restrict__ AT,
                                      int m, int n) {
    __shared__ float t[32][33];
    int bx = blockIdx.x * 32;
    int by = blockIdx.y * 32;
    int tx = threadIdx.x & 31, ty = threadIdx.x >> 5;   // 32 x 8
#pragma unroll
    for (int i = 0; i < 32; i += 8)
        t[ty + i][tx] = A[(size_t)(by + ty + i) * n + bx + tx];
    __syncthreads();
#pragma unroll
    for (int i = 0; i < 32; i += 8)
        AT[(size_t)(bx + ty + i) * m + by + tx] = f2h(t[tx][ty + i]);
}

// ---------------- fp16 MFMA GEMM, 64x128, 8 waves, 1-barrier 3-buffer --------
// C = X @ W^T. X=[M,K] fp16, W=[N,K] fp16. 512 thr = 8 waves.
// Tile 64Mx128N, BK=64, wave tile 32x32 (2x2 of 16x16x32 f16), waves 2Mx4N.
// XOR-swizzled LDS; XCD-aware 1D grid. 3 GLDS/thread/tile.
// K-loop: wait vmcnt -> barrier -> STAGE(kt+2) -> ds_read+MFMA. One barrier
// per tile; overwrite hazard ordered by the barrier (see header comment).
// Epilogue: acc -> LDS (f32, stride 132) -> thread-linear coalesced I/O.
// EPI: 0 Q:      lamOut = fp16(v)
//      1 c+lam1: cv=v-bvec[col]; cFout=cv; cHout=f2h(cv); lamOut=f2h(step*relu(cv))
//      2 iter:   nv=relu(h2f(lamIn) - step*(v - h2f(cH))); lamOut=f2h(nv)
//      3 iter*act
//      4 act:    actOut = (cF - v >= -TOL) ? 1 : 0  (fp16)
//      5 masked+lam1: mv=v*act; cHout=f2h(mv); lamOut=f2h(step*relu(mv))
//      6 final:  outF = uin - v
template<int EPI>
__global__ __launch_bounds__(512, 4)
void mfma_g(const ushort_t* __restrict__ X, const ushort_t* __restrict__ W,
            const ushort_t* __restrict__ lamIn, const float* __restrict__ cF,
            const ushort_t* __restrict__ cH, const ushort_t* __restrict__ actb,
            ushort_t* __restrict__ lamOut, float* __restrict__ cFout,
            ushort_t* __restrict__ cHout, ushort_t* __restrict__ actOut,
            const float* __restrict__ uin, float* __restrict__ outF,
            const float* __restrict__ bvec,
            int M, int N, int K) {
    // As[3][64*64] then Bs[3][128*64]; epilogue aliases front as [64][132] f32.
    __shared__ short SMEM[3 * 64 * 64 + 3 * 128 * 64];   // 72 KB, 2 blk/CU

    const int tid = threadIdx.x;
    const int w = tid >> 6;              // 0..7
    const int lane = tid & 63;

    const int nbm = M >> 6;
    const int spx = nbm >> 3;
    const int xcd = blockIdx.x & 7;
    const int loc = blockIdx.x >> 3;
    const int bm = (xcd * spx + (loc % spx)) << 6;
    const int bn = (loc / spx) << 7;

    const int wm = (w & 1) * 32;         // 2 wave-rows along M
    const int wn = (w >> 1) * 32;        // 4 wave-cols along N
    const int quad = lane >> 4;
    const int l15 = lane & 15;

    const int ldr = lane >> 3;
    const int csw = ((lane & 7) ^ ldr) * 8;

    const ushort_t* Xb = X + (size_t)bm * K + csw;
    const ushort_t* Wb = W + (size_t)bn * K + csw;

    floatx4 acc[2][2] = {};

    const int KT = K >> 6;

    short* const AsBase = SMEM;                 // 3 x 4096 shorts
    short* const BsBase = SMEM + 3 * 64 * 64;   // 3 x 8192 shorts

    // stage tile kt into buffer bi: 1 GLDS (As) + 2 GLDS (Bs) per thread
    auto STAGE = [&](int kt, int bi) {
        const int ko = kt << 6;
        GLDS(Xb + (size_t)(w * 8 + ldr) * K + ko, AsBase + bi * 4096 + (w * 8) * 64);
#pragma unroll
        for (int t = 0; t < 2; ++t)
            GLDS(Wb + (size_t)(w * 16 + t * 8 + ldr) * K + ko,
                 BsBase + bi * 8192 + (w * 16 + t * 8) * 64);
    };

    // prologue: stage tiles 0 and 1 (6 loads in flight)
    STAGE(0, 0);
    STAGE(1, 1);

    int cur = 0;
    for (int kt = 0; kt < KT; ++kt) {
        // per-wave wait: own stage(kt) loads landed; stage(kt+1) stays in flight
        if (kt + 1 < KT) {
            asm volatile("s_waitcnt vmcnt(3)" ::: "memory");
        } else {
            asm volatile("s_waitcnt vmcnt(0)" ::: "memory");
        }
        __builtin_amdgcn_s_barrier();          // buf[cur] valid for all waves;
                                               // also: no wave still reads
                                               // buf[(cur+2)%3] (its readers
                                               // finished before this barrier)
        if (kt + 2 < KT) {
            int nb = cur + 2; if (nb >= 3) nb -= 3;
            STAGE(kt + 2, nb);                 // overlaps this tile's compute
        }

        __builtin_amdgcn_s_setprio(1);
#pragma unroll
        for (int kk = 0; kk < 2; ++kk) {
            const int sw = ((kk * 4 + quad) ^ (l15 & 7)) * 8;
            half8 af[2], bfr[2];
#pragma unroll
            for (int i = 0; i < 2; ++i)
                af[i] = *(const half8*)(AsBase + cur * 4096 + (wm + i * 16 + l15) * 64 + sw);
#pragma unroll
            for (int i = 0; i < 2; ++i)
                bfr[i] = *(const half8*)(BsBase + cur * 8192 + (wn + i * 16 + l15) * 64 + sw);
#pragma unroll
            for (int mt = 0; mt < 2; ++mt)
#pragma unroll
                for (int nt = 0; nt < 2; ++nt)
                    acc[mt][nt] = __builtin_amdgcn_mfma_f32_16x16x32_f16(
                        af[mt], bfr[nt], acc[mt][nt], 0, 0, 0);
        }
        __builtin_amdgcn_s_setprio(0);
        ++cur; if (cur >= 3) cur -= 3;
    }

    // ---- epilogue: acc -> LDS (f32, stride 132) -> thread-linear coalesced ----
    __syncthreads();                           // all waves done reading As/Bs
    float* Cs = (float*)SMEM;                  // 64 x 132 f32 = 33792 B

    // write acc in C/D layout: row = quad*4+r, col = lane&15 per 16x16 tile
#pragma unroll
    for (int mt = 0; mt < 2; ++mt)
#pragma unroll
        for (int nt = 0; nt < 2; ++nt)
#pragma unroll
            for (int r = 0; r < 4; ++r) {
                int rl = wm + mt * 16 + quad * 4 + r;
                int cl = wn + nt * 16 + l15;
                Cs[rl * 132 + cl] = acc[mt][nt][r];
            }
    __syncthreads();

    // linear phase: thread t -> row t>>3 (0..63), col chunk (t&7)*16
    const int rl = tid >> 3;
    const int c0 = (tid & 7) * 16;
    const int grow = bm + rl;
    const int gcol = bn + c0;
    const size_t gidx = (size_t)grow * N + gcol;

    float v[16];
#pragma unroll
    for (int j = 0; j < 4; ++j)
        *(floatx4*)(v + 4 * j) = *(const floatx4*)(Cs + rl * 132 + c0 + 4 * j);

    if (EPI == 0) {
        ushort_t hv[16];
#pragma unroll
        for (int j = 0; j < 16; ++j) hv[j] = f2h(v[j]);
        *(ushort8v*)(lamOut + gidx) = *(ushort8v*)hv;
        *(ushort8v*)(lamOut + gidx + 8) = *(ushort8v*)(hv + 8);
    } else if (EPI == 1) {
        float bv[16];
#pragma unroll
        for (int j = 0; j < 4; ++j)
            *(floatx4*)(bv + 4 * j) = *(const floatx4*)(bvec + gcol + 4 * j);
        ushort_t ch[16], lo[16];
        float cf[16];
#pragma unroll
        for (int j = 0; j < 16; ++j) {
            float cv = v[j] - bv[j];
            cf[j] = cv;
            ch[j] = f2h(cv);
            lo[j] = f2h(STEPV * fmaxf(cv, 0.0f));
        }
#pragma unroll
        for (int j = 0; j < 4; ++j)
            *(floatx4*)(cFout + gidx + 4 * j) = *(floatx4*)(cf + 4 * j);
        *(ushort8v*)(cHout + gidx) = *(ushort8v*)ch;
        *(ushort8v*)(cHout + gidx + 8) = *(ushort8v*)(ch + 8);
        *(ushort8v*)(lamOut + gidx) = *(ushort8v*)lo;
        *(ushort8v*)(lamOut + gidx + 8) = *(ushort8v*)(lo + 8);
    } else if (EPI == 2 || EPI == 3) {
        ushort_t li[16], ch[16], ab[16], lo[16];
        *(ushort8v*)li = *(const ushort8v*)(lamIn + gidx);
        *(ushort8v*)(li + 8) = *(const ushort8v*)(lamIn + gidx + 8);
        *(ushort8v*)ch = *(const ushort8v*)(cH + gidx);
        *(ushort8v*)(ch + 8) = *(const ushort8v*)(cH + gidx + 8);
        if (EPI == 3) {
            *(ushort8v*)ab = *(const ushort8v*)(actb + gidx);
            *(ushort8v*)(ab + 8) = *(const ushort8v*)(actb + gidx + 8);
        }
#pragma unroll
        for (int j = 0; j < 16; ++j) {
            float nv = fmaxf(fmaf(-STEPV, v[j] - h2f(ch[j]), h2f(li[j])), 0.0f);
            if (EPI == 3) nv *= h2f(ab[j]);
            lo[j] = f2h(nv);
        }
        *(ushort8v*)(lamOut + gidx) = *(ushort8v*)lo;
        *(ushort8v*)(lamOut + gidx + 8) = *(ushort8v*)(lo + 8);
    } else if (EPI == 4) {
        float cf[16];
#pragma unroll
        for (int j = 0; j < 4; ++j)
            *(floatx4*)(cf + 4 * j) = *(const floatx4*)(cF + gidx + 4 * j);
        ushort_t ao[16];
#pragma unroll
        for (int j = 0; j < 16; ++j)
            ao[j] = (cf[j] - v[j] >= -TOLV) ? (ushort_t)0x3C00 : (ushort_t)0;
        *(ushort8v*)(actOut + gidx) = *(ushort8v*)ao;
        *(ushort8v*)(actOut + gidx + 8) = *(ushort8v*)(ao + 8);
    } else if (EPI == 5) {
        ushort_t ab[16], ch[16], lo[16];
        *(ushort8v*)ab = *(const ushort8v*)(actb + gidx);
        *(ushort8v*)(ab + 8) = *(const ushort8v*)(actb + gidx + 8);
#pragma unroll
        for (int j = 0; j < 16; ++j) {
            float mv = v[j] * h2f(ab[j]);
            ch[j] = f2h(mv);
            lo[j] = f2h(STEPV * fmaxf(mv, 0.0f));
        }
        *(ushort8v*)(cHout + gidx) = *(ushort8v*)ch;
        *(ushort8v*)(cHout + gidx + 8) = *(ushort8v*)(ch + 8);
        *(ushort8v*)(lamOut + gidx) = *(ushort8v*)lo;
        *(ushort8v*)(lamOut + gidx + 8) = *(ushort8v*)(lo + 8);
    } else if (EPI == 6) {
        float uv[16], ov[16];
#pragma unroll
        for (int j = 0; j < 4; ++j)
            *(floatx4*)(uv + 4 * j) = *(const floatx4*)(uin + gidx + 4 * j);
#pragma unroll
        for (int j = 0; j < 16; ++j) ov[j] = uv[j] - v[j];
#pragma unroll
        for (int j = 0; j < 4; ++j)
            *(floatx4*)(outF + gidx + 4 * j) = *(floatx4*)(ov + 4 * j);
    }
}

static inline int grid1d(int M, int N) { return (M >> 6) * (N >> 7); }

extern "C" void kernel_launch(void* const* d_in, const int* in_sizes, int n_in,
                              void* d_out, int out_size, void* d_ws, size_t ws_size,
                              hipStream_t stream) {
    const float* x = (const float*)d_in[0];  // [B,n]
    const float* u = (const float*)d_in[1];  // [B,n]
    const float* A = (const float*)d_in[2];  // [m,n]
    const float* b = (const float*)d_in[3];  // [m]
    float* out = (float*)d_out;              // [B,n]

    const int B = 4096, n = 512, m = 1024;
    const size_t Bm = (size_t)B * m;
    const size_t Bn = (size_t)B * n;

    ushort_t* A_h   = (ushort_t*)d_ws;             // [m,n]
    ushort_t* AT_h  = A_h + (size_t)m * n;         // [n,m]
    ushort_t* y_h   = AT_h + (size_t)n * m;        // [B,n]
    ushort_t* u_h   = y_h + Bn;                    // [B,n]
    ushort_t* Q_h   = u_h + Bn;                    // [m,m]
    ushort_t* lamA  = Q_h + (size_t)m * m;         // [B,m] fp16
    ushort_t* lamB  = lamA + Bm;                   // [B,m] fp16
    ushort_t* act   = lamB + Bm;                   // [B,m] fp16 0/1
    ushort_t* cHbuf = act + Bm;                    // [B,m] fp16 (c, then masked)
    float* cFbuf = (float*)(cHbuf + Bm);           // [B,m] f32 (c, for act test)

    dim3 blk(512);

    addcast_kernel<<<(int)(Bn / 4 + 255) / 256, 256, 0, stream>>>(x, u, y_h, u_h, (int)Bn);
    cvt_h_kernel<<<(m * n / 4 + 255) / 256, 256, 0, stream>>>(A, A_h, m * n);
    transpose_cast_kernel<<<dim3(n / 32, m / 32), dim3(256), 0, stream>>>(A, AT_h, m, n);

    // Q = fp16(A @ A^T)
    mfma_g<0><<<grid1d(m, m), blk, 0, stream>>>(
        A_h, A_h, nullptr, nullptr, nullptr, nullptr,
        Q_h, nullptr, nullptr, nullptr, nullptr, nullptr, nullptr, m, m, n);

    // c = y@A^T - b (cF fp32 + cH fp16); lamA = fp16(lam1 = step*relu(c))
    mfma_g<1><<<grid1d(B, m), blk, 0, stream>>>(
        y_h, A_h, nullptr, nullptr, nullptr, nullptr,
        lamA, cFbuf, cHbuf, nullptr, nullptr, nullptr, b, B, m, n);

    // phase 1: 49 more iterations (lam fp16 ping-pong)
    ushort_t* lin = lamA; ushort_t* lout = lamB;
    for (int it = 0; it < 49; ++it) {
        mfma_g<2><<<grid1d(B, m), blk, 0, stream>>>(
            lin, Q_h, lin, nullptr, cHbuf, nullptr,
            lout, nullptr, nullptr, nullptr, nullptr, nullptr, nullptr, B, m, m);
        ushort_t* t = lin; lin = lout; lout = t;
    }

    // active = (c - lam50@Q >= -TOL)
    mfma_g<4><<<grid1d(B, m), blk, 0, stream>>>(
        lin, Q_h, nullptr, cFbuf, nullptr, nullptr,
        nullptr, nullptr, nullptr, act, nullptr, nullptr, nullptr, B, m, m);

    // masked = (u@A^T)*active -> cHbuf; lamA = fp16(lam1 = step*relu(masked))
    mfma_g<5><<<grid1d(B, m), blk, 0, stream>>>(
        u_h, A_h, nullptr, nullptr, nullptr, act,
        lamA, nullptr, cHbuf, nullptr, nullptr, nullptr, nullptr, B, m, n);

    // phase 2: 9 more iterations
    lin = lamA; lout = lamB;
    for (int it = 0; it < 9; ++it) {
        mfma_g<3><<<grid1d(B, m), blk, 0, stream>>>(
            lin, Q_h, lin, nullptr, cHbuf, act,
            lout, nullptr, nullptr, nullptr, nullptr, nullptr, nullptr, B, m, m);
        ushort_t* t = lin; lin = lout; lout = t;
    }

    // out = u - lam @ A
    mfma_g<6><<<grid1d(B, n), blk, 0, stream>>>(
        lin, AT_h, nullptr, nullptr, nullptr, nullptr,
        nullptr, nullptr, nullptr, nullptr, u, out, nullptr, B, n, m);
}